// Round 11
// baseline (187.194 us; speedup 1.0000x reference)
//
#include <hip/hip_runtime.h>
#include <hip/hip_bf16.h>
#include <math.h>

typedef float v4f __attribute__((ext_vector_type(4)));
typedef __bf16 bf16x8 __attribute__((ext_vector_type(8)));
typedef __bf16 bf16x4 __attribute__((ext_vector_type(4)));

#define NN   1024
#define INF  128
#define H0C  192
#define H1C  96

// ws byte offsets
#define WS_W0BF   0        // 24576 bf16 (A-frag order, BN0 scale folded)
#define WS_W1BF   49152    // 18432 bf16 (A-frag order, BN1 scale folded)
#define WS_BN0SW  86016    // 192 f32: [q][cm][r] = bias0[16cm+4q+r]
#define WS_BN1SW  86784    // 96 f32:  [q][mt][r] = bias1[16mt+4q+r]
#define WS_WOUTSW 87168    // 96 f32:  [q][mt][r] = wout[16mt+4q+r]
#define WS_CINV   87552    // 1024 f32

// ---------------------------------------------------------------------------
// Prep. A-frag (16x16x32): lane holds A[m=l16][k=quad*8+j];
// flat [(mtile*KS+ks)*64 + lane]*8 + j, m = channel, k = input dim.
// Biases and wout pre-swizzled to C-layout register order [q][mt][r].
// [validated round 7]
// ---------------------------------------------------------------------------
__global__ __launch_bounds__(256) void prep_kernel(
    const float* __restrict__ W0, const float* __restrict__ g0,
    const float* __restrict__ b0, const float* __restrict__ m0,
    const float* __restrict__ v0, const float* __restrict__ W1,
    const float* __restrict__ g1, const float* __restrict__ b1,
    const float* __restrict__ m1, const float* __restrict__ v1,
    const float* __restrict__ Wout, char* __restrict__ ws)
{
    int e = blockIdx.x * 256 + threadIdx.x;
    __bf16* w0bf = (__bf16*)(ws + WS_W0BF);
    __bf16* w1bf = (__bf16*)(ws + WS_W1BF);
    float* bn0sw = (float*)(ws + WS_BN0SW);
    float* bn1sw = (float*)(ws + WS_BN1SW);
    float* woutsw = (float*)(ws + WS_WOUTSW);
    if (e < 24576) {                       // W0: 12 mtiles x 4 ksteps
        int j = e & 7, lane = (e >> 3) & 63, t = e >> 9;
        int ks = t & 3, mt = t >> 2;
        int c = mt * 16 + (lane & 15);               // m = H0 channel
        int k = ks * 32 + ((lane >> 4) << 3) + j;    // k = input feature
        float s = g0[c] * rsqrtf(v0[c] + 1e-5f);
        w0bf[e] = (__bf16)(W0[c * INF + k] * s);
    } else if (e < 43008) {                // W1: 6 mtiles x 6 ksteps
        int e2 = e - 24576;
        int j = e2 & 7, lane = (e2 >> 3) & 63, t = e2 >> 9;
        int ks = t % 6, mt = t / 6;
        int c = mt * 16 + (lane & 15);               // m = H1 channel
        int k = ks * 32 + ((lane >> 4) << 3) + j;    // k = H0 channel
        float s = g1[c] * rsqrtf(v1[c] + 1e-5f);
        w1bf[e2] = (__bf16)(W1[c * H0C + k] * s);
    } else if (e < 43200) {                // bn0 bias swizzled [q][cm][r]
        int e3 = e - 43008;
        int q = e3 / 48, rem = e3 % 48, cm = rem >> 2, r = rem & 3;
        int c = cm * 16 + q * 4 + r;
        float s = g0[c] * rsqrtf(v0[c] + 1e-5f);
        bn0sw[e3] = b0[c] - m0[c] * s;
    } else if (e < 43296) {                // bn1 bias swizzled [q][mt][r]
        int e4 = e - 43200;
        int q = e4 / 24, rem = e4 % 24, mt = rem >> 2, r = rem & 3;
        int c = mt * 16 + q * 4 + r;
        float s = g1[c] * rsqrtf(v1[c] + 1e-5f);
        bn1sw[e4] = b1[c] - m1[c] * s;
    } else if (e < 43392) {                // wout swizzled [q][mt][r]
        int e5 = e - 43296;
        int q = e5 / 24, rem = e5 % 24, mt = rem >> 2, r = rem & 3;
        woutsw[e5] = Wout[mt * 16 + q * 4 + r];
    }
}

// ---------------------------------------------------------------------------
// Main kernel, R11: 6 waves/block (384 thr), channel-split BOTH layers.
// R10 lesson: occupancy was accumulator-bound (acc1=96 AGPR + 84 VGPR ~ 180
// -> 2 waves/SIMD). Here:
//  - Layer1: wave owns 2 ch-mtiles (12/6) x 8 pair-ntiles; acc1[2][8]=64 AGPR.
//  - Layer2: wave owns 1 H1-mtile x 8 ntiles; acc2[8]=32 AGPR. W1 slice per
//    wave = 6 KB (block total 36 KB vs R7's 144 KB -> 4x less L1/L2 traffic).
//  - Epilogue: per-wave 16-channel partial dot -> LDS [pair][6] -> 128
//    threads finalize (sum 6 + bias + sigmoid + direct & mirror store).
// LDS = 51200 (X 34.8K then H0 overlay) + 3072 partial = 54272 B ->
// 3 blocks/CU x 6 waves = 18 waves/CU (4.5/SIMD) vs R10's 2.3.
// Symmetry: triangular tiles bj >= 2*bi (4160 blocks); identical values at
// (i,j) and (j,i) [exactness used by cinv_kernel].
// ---------------------------------------------------------------------------
__global__ __launch_bounds__(384, 3) void edgenet_main(
    const float* __restrict__ feat, const char* __restrict__ ws,
    const float* __restrict__ boutp, float* __restrict__ sim_out)
{
    __shared__ __align__(16) char smem[54272];
    float* partial = (float*)(smem + 51200);     // [128 pairs][6 waves]
    const int tid = threadIdx.x;
    const int lane = tid & 63;
    const int wave = tid >> 6;                   // 0..5
    const int l16 = lane & 15;
    const int quad = lane >> 4;

    // decode triangular tile id -> (bi, bj): cum(bi) = bi*(129-bi)  [R2-verified]
    const int id = blockIdx.x;
    int bi = (int)((129.0f - sqrtf(16641.0f - 4.0f * (float)id)) * 0.5f);
    while (bi > 0 && bi * (129 - bi) > id) --bi;
    while ((bi + 1) * (128 - bi) <= id) ++bi;
    const int bj = 2 * bi + (id - bi * (129 - bi));
    const int i0 = bi << 4;
    const int j0 = bj << 3;

    // ---- X gen: 2048 chunk-tasks strided over 384 threads ----
    for (int c = tid; c < 2048; c += 384) {
        int p = c >> 4;                // pair = jj*16 + ii
        int f0 = (c & 15) << 3;
        int ii = p & 15, jj = p >> 4;
        const float* fi = feat + (i0 + ii) * INF + f0;
        const float* fj = feat + (j0 + jj) * INF + f0;
        float4 a0 = *(const float4*)fi;
        float4 a1 = *(const float4*)(fi + 4);
        float4 q0 = *(const float4*)fj;
        float4 q1 = *(const float4*)(fj + 4);
        bf16x8 x;
        x[0] = (__bf16)fabsf(a0.x - q0.x);
        x[1] = (__bf16)fabsf(a0.y - q0.y);
        x[2] = (__bf16)fabsf(a0.z - q0.z);
        x[3] = (__bf16)fabsf(a0.w - q0.w);
        x[4] = (__bf16)fabsf(a1.x - q1.x);
        x[5] = (__bf16)fabsf(a1.y - q1.y);
        x[6] = (__bf16)fabsf(a1.z - q1.z);
        x[7] = (__bf16)fabsf(a1.w - q1.w);
        *(bf16x8*)(smem + p * 272 + f0 * 2) = x;
    }
    __syncthreads();

    const bf16x8* w0v = (const bf16x8*)(ws + WS_W0BF);
    const bf16x8* w1v = (const bf16x8*)(ws + WS_W1BF);
    const float* bn0sw = (const float*)(ws + WS_BN0SW);
    const float* bn1sw = (const float*)(ws + WS_BN1SW);

    // ---- Layer 1: wave owns ch-mtiles cm = 2*wave + mt, all 128 pairs ----
    v4f acc1[2][8];
    #pragma unroll
    for (int mt = 0; mt < 2; ++mt) {
        v4f bb = *(const v4f*)(bn0sw + (quad * 12 + wave * 2 + mt) * 4);
        #pragma unroll
        for (int nt = 0; nt < 8; ++nt)
            acc1[mt][nt] = bb;
    }
    #pragma unroll
    for (int ks = 0; ks < 4; ++ks) {
        bf16x8 w0a = w0v[((wave * 2 + 0) * 4 + ks) * 64 + lane];
        bf16x8 w0b = w0v[((wave * 2 + 1) * 4 + ks) * 64 + lane];
        #pragma unroll
        for (int nt = 0; nt < 8; ++nt) {
            bf16x8 xk = *(const bf16x8*)(smem +
                (nt * 16 + l16) * 272 + ks * 64 + quad * 16);
            acc1[0][nt] = __builtin_amdgcn_mfma_f32_16x16x32_bf16(
                w0a, xk, acc1[0][nt], 0, 0, 0);
            acc1[1][nt] = __builtin_amdgcn_mfma_f32_16x16x32_bf16(
                w0b, xk, acc1[1][nt], 0, 0, 0);
        }
    }
    __syncthreads();   // all X reads done; H0 overlays

    // ---- H0 write: leaky + pack 4 consecutive channels -> ds_write_b64 ----
    #pragma unroll
    for (int mt = 0; mt < 2; ++mt) {
        int chb = (wave * 2 + mt) * 16 + quad * 4;
        #pragma unroll
        for (int nt = 0; nt < 8; ++nt) {
            bf16x4 pk;
            #pragma unroll
            for (int r = 0; r < 4; ++r) {
                float v = acc1[mt][nt][r];
                v = fmaxf(v, 0.01f * v);
                pk[r] = (__bf16)v;
            }
            *(bf16x4*)(smem + (nt * 16 + l16) * 400 + chb * 2) = pk;
        }
    }
    __syncthreads();   // H0 complete (cross-wave channels)

    // ---- Layer 2: wave owns H1-mtile = wave, all 8 pair-ntiles ----
    v4f acc2[8];
    {
        v4f bb = *(const v4f*)(bn1sw + (quad * 6 + wave) * 4);
        #pragma unroll
        for (int nt = 0; nt < 8; ++nt)
            acc2[nt] = bb;
    }
    #pragma unroll
    for (int ks = 0; ks < 6; ++ks) {
        bf16x8 w = w1v[(wave * 6 + ks) * 64 + lane];
        #pragma unroll
        for (int nt = 0; nt < 8; ++nt) {
            bf16x8 h = *(const bf16x8*)(smem +
                (nt * 16 + l16) * 400 + ks * 64 + quad * 16);
            acc2[nt] = __builtin_amdgcn_mfma_f32_16x16x32_bf16(
                w, h, acc2[nt], 0, 0, 0);
        }
    }

    // ---- per-wave partial dot over its 16 channels + quad butterfly ----
    const float* woutsw = (const float*)(ws + WS_WOUTSW);
    v4f wo = *(const v4f*)(woutsw + (quad * 6 + wave) * 4);
    float part[8];
    #pragma unroll
    for (int nt = 0; nt < 8; ++nt) {
        float s = 0.f;
        #pragma unroll
        for (int r = 0; r < 4; ++r) {
            float v = acc2[nt][r];
            v = fmaxf(v, 0.01f * v);
            s = fmaf(v, wo[r], s);
        }
        s += __shfl_xor(s, 16, 64);
        s += __shfl_xor(s, 32, 64);
        part[nt] = s;      // replicated over quads
    }
    // quad q writes ntiles {2q, 2q+1} -> partial[pair][wave]
    #pragma unroll
    for (int t = 0; t < 2; ++t) {
        int nt = 2 * quad + t;
        partial[(nt * 16 + l16) * 6 + wave] = part[nt];
    }
    __syncthreads();

    // ---- finalize: 128 threads sum 6 partials, sigmoid, store both ----
    if (tid < 128) {
        int ii = tid & 15, jj = tid >> 4;
        float s = partial[tid * 6 + 0] + partial[tid * 6 + 1]
                + partial[tid * 6 + 2] + partial[tid * 6 + 3]
                + partial[tid * 6 + 4] + partial[tid * 6 + 5];
        float sv = 1.f / (1.f + expf(-(s + boutp[0])));
        sim_out[(i0 + ii) * NN + (j0 + jj)] = sv;   // direct
        sim_out[(j0 + jj) * NN + (i0 + ii)] = sv;   // mirror (64B runs per jj)
    }
}

// ---------------------------------------------------------------------------
// cinv via EXACT symmetry: colsum[j] == rowsum(sim[j][*]). [R9-verified]
// ---------------------------------------------------------------------------
__global__ __launch_bounds__(256) void cinv_kernel(
    const float* __restrict__ sim, float* __restrict__ cinv)
{
    const int lane = threadIdx.x & 63;
    const int wave = threadIdx.x >> 6;
    const float cadd = 1.0f + (float)NN * 1e-6f;
    #pragma unroll
    for (int rr = 0; rr < 4; ++rr) {
        int j = blockIdx.x * 16 + wave * 4 + rr;
        const float4* row = (const float4*)(sim + j * NN);
        float4 a0 = row[lane];
        float4 a1 = row[lane + 64];
        float4 a2 = row[lane + 128];
        float4 a3 = row[lane + 192];
        float s = (a0.x + a0.y + a0.z + a0.w) + (a1.x + a1.y + a1.z + a1.w)
                + (a2.x + a2.y + a2.z + a2.w) + (a3.x + a3.y + a3.z + a3.w);
        #pragma unroll
        for (int off = 1; off < 64; off <<= 1)
            s += __shfl_xor(s, off, 64);
        if (lane == 0)
            cinv[j] = 1.0f / (s + cadd);
    }
}

// ---------------------------------------------------------------------------
// edge[i][j] = (sim + eye + 1e-6) * cinv[j].
// ---------------------------------------------------------------------------
__global__ __launch_bounds__(256) void edge_kernel(
    const float* __restrict__ cinv, const float* __restrict__ sim,
    float* __restrict__ edge)
{
    int i = blockIdx.x;
    int jc = threadIdx.x << 2;
    float4 w = *(const float4*)(cinv + jc);
    float4 s = *(const float4*)(sim + i * NN + jc);
    float4 o;
    o.x = (s.x + (i == jc + 0 ? 1.f : 0.f) + 1e-6f) * w.x;
    o.y = (s.y + (i == jc + 1 ? 1.f : 0.f) + 1e-6f) * w.y;
    o.z = (s.z + (i == jc + 2 ? 1.f : 0.f) + 1e-6f) * w.z;
    o.w = (s.w + (i == jc + 3 ? 1.f : 0.f) + 1e-6f) * w.w;
    *(float4*)(edge + i * NN + jc) = o;
}

extern "C" void kernel_launch(void* const* d_in, const int* in_sizes, int n_in,
                              void* d_out, int out_size, void* d_ws, size_t ws_size,
                              hipStream_t stream)
{
    const float* feat = (const float*)d_in[0];
    const float* W0   = (const float*)d_in[1];
    const float* g0   = (const float*)d_in[2];
    const float* b0   = (const float*)d_in[3];
    const float* m0   = (const float*)d_in[4];
    const float* v0   = (const float*)d_in[5];
    const float* W1   = (const float*)d_in[6];
    const float* g1   = (const float*)d_in[7];
    const float* b1   = (const float*)d_in[8];
    const float* m1   = (const float*)d_in[9];
    const float* v1   = (const float*)d_in[10];
    const float* Wout = (const float*)d_in[11];
    const float* bout = (const float*)d_in[12];
    char* ws = (char*)d_ws;
    float* edge = (float*)d_out;
    float* sim  = edge + NN * NN;
    float* cinv = (float*)(ws + WS_CINV);

    prep_kernel<<<dim3(170), dim3(256), 0, stream>>>(
        W0, g0, b0, m0, v0, W1, g1, b1, m1, v1, Wout, ws);
    edgenet_main<<<dim3(4160), dim3(384), 0, stream>>>(feat, ws, bout, sim);
    cinv_kernel<<<dim3(64), dim3(256), 0, stream>>>(sim, cinv);
    edge_kernel<<<dim3(1024), dim3(256), 0, stream>>>(cinv, sim, edge);
}

// Round 12
// 171.478 us; speedup vs baseline: 1.0917x; 1.0917x over previous
//
#include <hip/hip_runtime.h>
#include <hip/hip_bf16.h>
#include <math.h>

typedef float v4f __attribute__((ext_vector_type(4)));
typedef __bf16 bf16x8 __attribute__((ext_vector_type(8)));
typedef __bf16 bf16x4 __attribute__((ext_vector_type(4)));

#define NN   1024
#define INF  128
#define H0C  192
#define H1C  96

// ws byte offsets
#define WS_W0BF   0        // 24576 bf16 (A-frag order, BN0 scale folded)
#define WS_W1BF   49152    // 18432 bf16 (A-frag order, BN1 scale folded)
#define WS_BN0SW  86016    // 192 f32: [q][cm][r] = bias0[16cm+4q+r]
#define WS_BN1SW  86784    // 96 f32:  [q][mt][r] = bias1[16mt+4q+r]
#define WS_WOUTSW 87168    // 96 f32:  [q][mt][r] = wout[16mt+4q+r]
#define WS_CINV   87552    // 1024 f32

// ---------------------------------------------------------------------------
// Prep. A-frag (16x16x32): lane holds A[m=l16][k=quad*8+j];
// flat [(mtile*KS+ks)*64 + lane]*8 + j, m = channel, k = input dim.
// Biases and wout pre-swizzled to C-layout register order [q][mt][r].
// [validated round 7]
// ---------------------------------------------------------------------------
__global__ __launch_bounds__(256) void prep_kernel(
    const float* __restrict__ W0, const float* __restrict__ g0,
    const float* __restrict__ b0, const float* __restrict__ m0,
    const float* __restrict__ v0, const float* __restrict__ W1,
    const float* __restrict__ g1, const float* __restrict__ b1,
    const float* __restrict__ m1, const float* __restrict__ v1,
    const float* __restrict__ Wout, char* __restrict__ ws)
{
    int e = blockIdx.x * 256 + threadIdx.x;
    __bf16* w0bf = (__bf16*)(ws + WS_W0BF);
    __bf16* w1bf = (__bf16*)(ws + WS_W1BF);
    float* bn0sw = (float*)(ws + WS_BN0SW);
    float* bn1sw = (float*)(ws + WS_BN1SW);
    float* woutsw = (float*)(ws + WS_WOUTSW);
    if (e < 24576) {                       // W0: 12 mtiles x 4 ksteps
        int j = e & 7, lane = (e >> 3) & 63, t = e >> 9;
        int ks = t & 3, mt = t >> 2;
        int c = mt * 16 + (lane & 15);               // m = H0 channel
        int k = ks * 32 + ((lane >> 4) << 3) + j;    // k = input feature
        float s = g0[c] * rsqrtf(v0[c] + 1e-5f);
        w0bf[e] = (__bf16)(W0[c * INF + k] * s);
    } else if (e < 43008) {                // W1: 6 mtiles x 6 ksteps
        int e2 = e - 24576;
        int j = e2 & 7, lane = (e2 >> 3) & 63, t = e2 >> 9;
        int ks = t % 6, mt = t / 6;
        int c = mt * 16 + (lane & 15);               // m = H1 channel
        int k = ks * 32 + ((lane >> 4) << 3) + j;    // k = H0 channel
        float s = g1[c] * rsqrtf(v1[c] + 1e-5f);
        w1bf[e2] = (__bf16)(W1[c * H0C + k] * s);
    } else if (e < 43200) {                // bn0 bias swizzled [q][cm][r]
        int e3 = e - 43008;
        int q = e3 / 48, rem = e3 % 48, cm = rem >> 2, r = rem & 3;
        int c = cm * 16 + q * 4 + r;
        float s = g0[c] * rsqrtf(v0[c] + 1e-5f);
        bn0sw[e3] = b0[c] - m0[c] * s;
    } else if (e < 43296) {                // bn1 bias swizzled [q][mt][r]
        int e4 = e - 43200;
        int q = e4 / 24, rem = e4 % 24, mt = rem >> 2, r = rem & 3;
        int c = mt * 16 + q * 4 + r;
        float s = g1[c] * rsqrtf(v1[c] + 1e-5f);
        bn1sw[e4] = b1[c] - m1[c] * s;
    } else if (e < 43392) {                // wout swizzled [q][mt][r]
        int e5 = e - 43296;
        int q = e5 / 24, rem = e5 % 24, mt = rem >> 2, r = rem & 3;
        woutsw[e5] = Wout[mt * 16 + q * 4 + r];
    }
}

// ---------------------------------------------------------------------------
// Main kernel, R12: 8 waves/block (512 thr), R7 dataflow with the per-wave
// accumulator halved (R10/R11 lesson: occupancy is accumulator-bound, and
// acc regs = tile-pairs-owned x 4, reducible only via more waves/block).
//  - Layer1: wave owns mt-triple (w>>1) x nt-half (w&1): 3mt x 4nt,
//    acc1[3][4] = 48 AGPR (was 96).
//  - Layer2: wave owns pair-ntile = wave (jj = wave), all 6 mt; acc2[6] = 24.
//    Identical LDS pattern + epilogue reduction order as R7 (absmax 3.9e-3).
//  - LDS unchanged 51200 B -> 2 blocks/CU = 16 waves/CU = 4 waves/SIMD
//    (vs R10's 2.3). Same MFMA count, 3 barriers, same traffic.
// Symmetry: triangular tiles bj >= 2*bi (4160 blocks); identical values at
// (i,j) and (j,i) [exactness used by cinv_kernel].
// ---------------------------------------------------------------------------
__global__ __launch_bounds__(512, 3) void edgenet_main(
    const float* __restrict__ feat, const char* __restrict__ ws,
    const float* __restrict__ boutp, float* __restrict__ sim_out)
{
    __shared__ __align__(16) char smem[51200];   // X then H0 (overlay)
    const int tid = threadIdx.x;
    const int lane = tid & 63;
    const int wave = tid >> 6;                   // 0..7
    const int l16 = lane & 15;
    const int quad = lane >> 4;

    // decode triangular tile id -> (bi, bj): cum(bi) = bi*(129-bi)  [R2-verified]
    const int id = blockIdx.x;
    int bi = (int)((129.0f - sqrtf(16641.0f - 4.0f * (float)id)) * 0.5f);
    while (bi > 0 && bi * (129 - bi) > id) --bi;
    while ((bi + 1) * (128 - bi) <= id) ++bi;
    const int bj = 2 * bi + (id - bi * (129 - bi));
    const int i0 = bi << 4;
    const int j0 = bj << 3;

    // ---- X gen: 2048 chunk-tasks over 512 threads (4 each) [R11-verified] --
    #pragma unroll
    for (int it = 0; it < 4; ++it) {
        int c = it * 512 + tid;
        int p = c >> 4;                // pair = jj*16 + ii
        int f0 = (c & 15) << 3;
        int ii = p & 15, jj = p >> 4;
        const float* fi = feat + (i0 + ii) * INF + f0;
        const float* fj = feat + (j0 + jj) * INF + f0;
        float4 a0 = *(const float4*)fi;
        float4 a1 = *(const float4*)(fi + 4);
        float4 q0 = *(const float4*)fj;
        float4 q1 = *(const float4*)(fj + 4);
        bf16x8 x;
        x[0] = (__bf16)fabsf(a0.x - q0.x);
        x[1] = (__bf16)fabsf(a0.y - q0.y);
        x[2] = (__bf16)fabsf(a0.z - q0.z);
        x[3] = (__bf16)fabsf(a0.w - q0.w);
        x[4] = (__bf16)fabsf(a1.x - q1.x);
        x[5] = (__bf16)fabsf(a1.y - q1.y);
        x[6] = (__bf16)fabsf(a1.z - q1.z);
        x[7] = (__bf16)fabsf(a1.w - q1.w);
        *(bf16x8*)(smem + p * 272 + f0 * 2) = x;
    }
    __syncthreads();

    const bf16x8* w0v = (const bf16x8*)(ws + WS_W0BF);
    const bf16x8* w1v = (const bf16x8*)(ws + WS_W1BF);
    const float* bn0sw = (const float*)(ws + WS_BN0SW);
    const float* bn1sw = (const float*)(ws + WS_BN1SW);

    // ---- Layer 1: wave owns mt-triple (w>>1), nt-half (w&1) ----
    const int mtbase = (wave >> 1) * 3;          // 0,3,6,9
    const int ntbase = (wave & 1) * 4;           // 0 or 4
    v4f acc1[3][4];
    #pragma unroll
    for (int mt = 0; mt < 3; ++mt) {
        v4f bb = *(const v4f*)(bn0sw + (quad * 12 + mtbase + mt) * 4);
        #pragma unroll
        for (int nt = 0; nt < 4; ++nt)
            acc1[mt][nt] = bb;
    }
    #pragma unroll
    for (int ks = 0; ks < 4; ++ks) {
        bf16x8 w0a = w0v[((mtbase + 0) * 4 + ks) * 64 + lane];
        bf16x8 w0b = w0v[((mtbase + 1) * 4 + ks) * 64 + lane];
        bf16x8 w0c = w0v[((mtbase + 2) * 4 + ks) * 64 + lane];
        #pragma unroll
        for (int nt = 0; nt < 4; ++nt) {
            bf16x8 xk = *(const bf16x8*)(smem +
                ((ntbase + nt) * 16 + l16) * 272 + ks * 64 + quad * 16);
            acc1[0][nt] = __builtin_amdgcn_mfma_f32_16x16x32_bf16(
                w0a, xk, acc1[0][nt], 0, 0, 0);
            acc1[1][nt] = __builtin_amdgcn_mfma_f32_16x16x32_bf16(
                w0b, xk, acc1[1][nt], 0, 0, 0);
            acc1[2][nt] = __builtin_amdgcn_mfma_f32_16x16x32_bf16(
                w0c, xk, acc1[2][nt], 0, 0, 0);
        }
    }
    __syncthreads();   // all X reads done; H0 may overlay

    // ---- H0 write: leaky + pack 4 consecutive channels -> ds_write_b64 ----
    #pragma unroll
    for (int mt = 0; mt < 3; ++mt) {
        int chb = (mtbase + mt) * 16 + quad * 4;
        #pragma unroll
        for (int nt = 0; nt < 4; ++nt) {
            bf16x4 pk;
            #pragma unroll
            for (int r = 0; r < 4; ++r) {
                float v = acc1[mt][nt][r];
                v = fmaxf(v, 0.01f * v);
                pk[r] = (__bf16)v;
            }
            *(bf16x4*)(smem + ((ntbase + nt) * 16 + l16) * 400 + chb * 2) = pk;
        }
    }
    __syncthreads();   // H0 complete (cross-wave channels)

    // ---- Layer 2: wave owns pair-ntile = wave (jj = wave), all 6 mt ----
    v4f acc2[6];
    #pragma unroll
    for (int mt = 0; mt < 6; ++mt) {
        float* a = (float*)&acc2[mt];
        v4f bb = *(const v4f*)(bn1sw + (quad * 6 + mt) * 4);
        acc2[mt] = bb;
        (void)a;
    }
    #pragma unroll
    for (int ks = 0; ks < 6; ++ks) {
        bf16x8 h = *(const bf16x8*)(smem +
            (wave * 16 + l16) * 400 + ks * 64 + quad * 16);
        #pragma unroll
        for (int mt = 0; mt < 6; ++mt) {
            bf16x8 w = w1v[(mt * 6 + ks) * 64 + lane];
            acc2[mt] = __builtin_amdgcn_mfma_f32_16x16x32_bf16(
                w, h, acc2[mt], 0, 0, 0);
        }
    }

    // ---- epilogue: leaky + dot(wout) + cross-quad butterfly + sigmoid ----
    // (identical reduction order to R7 -> absmax 3.9e-3)
    const float* woutsw = (const float*)(ws + WS_WOUTSW);
    float part = 0.f;
    #pragma unroll
    for (int mt = 0; mt < 6; ++mt) {
        v4f wo = *(const v4f*)(woutsw + (quad * 6 + mt) * 4);
        #pragma unroll
        for (int r = 0; r < 4; ++r) {
            float v = acc2[mt][r];
            v = fmaxf(v, 0.01f * v);
            part = fmaf(v, wo[r], part);
        }
    }
    part += __shfl_xor(part, 16, 64);
    part += __shfl_xor(part, 32, 64);
    // lane (q,l16) holds the full logit for pair (i0+l16, j0+wave),
    // replicated over quads.
    float sv = 1.f / (1.f + expf(-(part + boutp[0])));
    if (quad == 0)
        sim_out[(i0 + l16) * NN + j0 + wave] = sv;          // direct (strided)
    else if (quad == 1)
        sim_out[(j0 + wave) * NN + i0 + l16] = sv;          // mirror (64B run)
}

// ---------------------------------------------------------------------------
// cinv via EXACT symmetry: colsum[j] == rowsum(sim[j][*]). [R9-verified]
// ---------------------------------------------------------------------------
__global__ __launch_bounds__(256) void cinv_kernel(
    const float* __restrict__ sim, float* __restrict__ cinv)
{
    const int lane = threadIdx.x & 63;
    const int wave = threadIdx.x >> 6;
    const float cadd = 1.0f + (float)NN * 1e-6f;
    #pragma unroll
    for (int rr = 0; rr < 4; ++rr) {
        int j = blockIdx.x * 16 + wave * 4 + rr;
        const float4* row = (const float4*)(sim + j * NN);
        float4 a0 = row[lane];
        float4 a1 = row[lane + 64];
        float4 a2 = row[lane + 128];
        float4 a3 = row[lane + 192];
        float s = (a0.x + a0.y + a0.z + a0.w) + (a1.x + a1.y + a1.z + a1.w)
                + (a2.x + a2.y + a2.z + a2.w) + (a3.x + a3.y + a3.z + a3.w);
        #pragma unroll
        for (int off = 1; off < 64; off <<= 1)
            s += __shfl_xor(s, off, 64);
        if (lane == 0)
            cinv[j] = 1.0f / (s + cadd);
    }
}

// ---------------------------------------------------------------------------
// edge[i][j] = (sim + eye + 1e-6) * cinv[j].
// ---------------------------------------------------------------------------
__global__ __launch_bounds__(256) void edge_kernel(
    const float* __restrict__ cinv, const float* __restrict__ sim,
    float* __restrict__ edge)
{
    int i = blockIdx.x;
    int jc = threadIdx.x << 2;
    float4 w = *(const float4*)(cinv + jc);
    float4 s = *(const float4*)(sim + i * NN + jc);
    float4 o;
    o.x = (s.x + (i == jc + 0 ? 1.f : 0.f) + 1e-6f) * w.x;
    o.y = (s.y + (i == jc + 1 ? 1.f : 0.f) + 1e-6f) * w.y;
    o.z = (s.z + (i == jc + 2 ? 1.f : 0.f) + 1e-6f) * w.z;
    o.w = (s.w + (i == jc + 3 ? 1.f : 0.f) + 1e-6f) * w.w;
    *(float4*)(edge + i * NN + jc) = o;
}

extern "C" void kernel_launch(void* const* d_in, const int* in_sizes, int n_in,
                              void* d_out, int out_size, void* d_ws, size_t ws_size,
                              hipStream_t stream)
{
    const float* feat = (const float*)d_in[0];
    const float* W0   = (const float*)d_in[1];
    const float* g0   = (const float*)d_in[2];
    const float* b0   = (const float*)d_in[3];
    const float* m0   = (const float*)d_in[4];
    const float* v0   = (const float*)d_in[5];
    const float* W1   = (const float*)d_in[6];
    const float* g1   = (const float*)d_in[7];
    const float* b1   = (const float*)d_in[8];
    const float* m1   = (const float*)d_in[9];
    const float* v1   = (const float*)d_in[10];
    const float* Wout = (const float*)d_in[11];
    const float* bout = (const float*)d_in[12];
    char* ws = (char*)d_ws;
    float* edge = (float*)d_out;
    float* sim  = edge + NN * NN;
    float* cinv = (float*)(ws + WS_CINV);

    prep_kernel<<<dim3(170), dim3(256), 0, stream>>>(
        W0, g0, b0, m0, v0, W1, g1, b1, m1, v1, Wout, ws);
    edgenet_main<<<dim3(4160), dim3(512), 0, stream>>>(feat, ws, bout, sim);
    cinv_kernel<<<dim3(64), dim3(256), 0, stream>>>(sim, cinv);
    edge_kernel<<<dim3(1024), dim3(256), 0, stream>>>(cinv, sim, edge);
}

// Round 13
// 148.417 us; speedup vs baseline: 1.2613x; 1.1554x over previous
//
#include <hip/hip_runtime.h>
#include <hip/hip_bf16.h>
#include <math.h>

typedef float v4f __attribute__((ext_vector_type(4)));
typedef __bf16 bf16x8 __attribute__((ext_vector_type(8)));
typedef __bf16 bf16x4 __attribute__((ext_vector_type(4)));

#define NN   1024
#define INF  128
#define H0C  192
#define H1C  96

// ws byte offsets
#define WS_W0BF   0        // 24576 bf16 (A-frag order, BN0 scale folded)
#define WS_W1BF   49152    // 18432 bf16 (A-frag order, BN1 scale folded)
#define WS_BN0SW  86016    // 192 f32: [q][cm][r] = bias0[16cm+4q+r]
#define WS_BN1SW  86784    // 96 f32:  [q][mt][r] = bias1[16mt+4q+r]
#define WS_WOUTSW 87168    // 96 f32:  [q][mt][r] = wout[16mt+4q+r]
#define WS_CINV   87552    // 1024 f32

// ---------------------------------------------------------------------------
// Prep. A-frag (16x16x32): lane holds A[m=l16][k=quad*8+j];
// flat [(mtile*KS+ks)*64 + lane]*8 + j, m = channel, k = input dim.
// Biases and wout pre-swizzled to C-layout register order [q][mt][r].
// [validated round 7]
// ---------------------------------------------------------------------------
__global__ __launch_bounds__(256) void prep_kernel(
    const float* __restrict__ W0, const float* __restrict__ g0,
    const float* __restrict__ b0, const float* __restrict__ m0,
    const float* __restrict__ v0, const float* __restrict__ W1,
    const float* __restrict__ g1, const float* __restrict__ b1,
    const float* __restrict__ m1, const float* __restrict__ v1,
    const float* __restrict__ Wout, char* __restrict__ ws)
{
    int e = blockIdx.x * 256 + threadIdx.x;
    __bf16* w0bf = (__bf16*)(ws + WS_W0BF);
    __bf16* w1bf = (__bf16*)(ws + WS_W1BF);
    float* bn0sw = (float*)(ws + WS_BN0SW);
    float* bn1sw = (float*)(ws + WS_BN1SW);
    float* woutsw = (float*)(ws + WS_WOUTSW);
    if (e < 24576) {                       // W0: 12 mtiles x 4 ksteps
        int j = e & 7, lane = (e >> 3) & 63, t = e >> 9;
        int ks = t & 3, mt = t >> 2;
        int c = mt * 16 + (lane & 15);               // m = H0 channel
        int k = ks * 32 + ((lane >> 4) << 3) + j;    // k = input feature
        float s = g0[c] * rsqrtf(v0[c] + 1e-5f);
        w0bf[e] = (__bf16)(W0[c * INF + k] * s);
    } else if (e < 43008) {                // W1: 6 mtiles x 6 ksteps
        int e2 = e - 24576;
        int j = e2 & 7, lane = (e2 >> 3) & 63, t = e2 >> 9;
        int ks = t % 6, mt = t / 6;
        int c = mt * 16 + (lane & 15);               // m = H1 channel
        int k = ks * 32 + ((lane >> 4) << 3) + j;    // k = H0 channel
        float s = g1[c] * rsqrtf(v1[c] + 1e-5f);
        w1bf[e2] = (__bf16)(W1[c * H0C + k] * s);
    } else if (e < 43200) {                // bn0 bias swizzled [q][cm][r]
        int e3 = e - 43008;
        int q = e3 / 48, rem = e3 % 48, cm = rem >> 2, r = rem & 3;
        int c = cm * 16 + q * 4 + r;
        float s = g0[c] * rsqrtf(v0[c] + 1e-5f);
        bn0sw[e3] = b0[c] - m0[c] * s;
    } else if (e < 43296) {                // bn1 bias swizzled [q][mt][r]
        int e4 = e - 43200;
        int q = e4 / 24, rem = e4 % 24, mt = rem >> 2, r = rem & 3;
        int c = mt * 16 + q * 4 + r;
        float s = g1[c] * rsqrtf(v1[c] + 1e-5f);
        bn1sw[e4] = b1[c] - m1[c] * s;
    } else if (e < 43392) {                // wout swizzled [q][mt][r]
        int e5 = e - 43296;
        int q = e5 / 24, rem = e5 % 24, mt = rem >> 2, r = rem & 3;
        woutsw[e5] = Wout[mt * 16 + q * 4 + r];
    }
}

// ---------------------------------------------------------------------------
// Main kernel, R13: exact R7/R10 shape (4 waves, 128 pairs, unique weight
// slices per wave — the weight-traffic optimum per R12's regression), with
// layer-1's accumulator halved TEMPORALLY: two nt-halves of 4, each half's
// acc (48 AGPR) leaky+bf16-packed into VGPRs (48) before the next half.
// Peak unified regs ~150 (was 180) -> 3 waves/SIMD at IDENTICAL weight
// traffic (W0 frags re-read once, L1-hot within-wave).
// Symmetry: triangular tiles bj >= 2*bi (4160 blocks); identical values at
// (i,j) and (j,i) [exactness used by cinv_kernel].
// ---------------------------------------------------------------------------
__global__ __launch_bounds__(256, 3) void edgenet_main(
    const float* __restrict__ feat, const char* __restrict__ ws,
    const float* __restrict__ boutp, float* __restrict__ sim_out)
{
    __shared__ __align__(16) char smem[51200];   // X then H0 (overlay)
    const int tid = threadIdx.x;
    const int lane = tid & 63;
    const int wave = tid >> 6;
    const int l16 = lane & 15;
    const int quad = lane >> 4;

    // decode triangular tile id -> (bi, bj): cum(bi) = bi*(129-bi)  [R2-verified]
    const int id = blockIdx.x;
    int bi = (int)((129.0f - sqrtf(16641.0f - 4.0f * (float)id)) * 0.5f);
    while (bi > 0 && bi * (129 - bi) > id) --bi;
    while ((bi + 1) * (128 - bi) <= id) ++bi;
    const int bj = 2 * bi + (id - bi * (129 - bi));
    const int i0 = bi << 4;
    const int j0 = bj << 3;
    const int jb = j0 + wave * 2;

    // ---- X gen: fi once, stream 8 fj rows [R8-verified] ----
    {
        int ii = tid & 15, fblk = tid >> 4;
        const float* fi = feat + (i0 + ii) * INF + fblk * 8;
        float4 a0 = *(const float4*)fi;
        float4 a1 = *(const float4*)(fi + 4);
        const float* fj = feat + j0 * INF + fblk * 8;
        char* sp = smem + ii * 272 + fblk * 16;
        #pragma unroll
        for (int jj = 0; jj < 8; ++jj) {
            float4 q0 = *(const float4*)fj;
            float4 q1 = *(const float4*)(fj + 4);
            bf16x8 x;
            x[0] = (__bf16)fabsf(a0.x - q0.x);
            x[1] = (__bf16)fabsf(a0.y - q0.y);
            x[2] = (__bf16)fabsf(a0.z - q0.z);
            x[3] = (__bf16)fabsf(a0.w - q0.w);
            x[4] = (__bf16)fabsf(a1.x - q1.x);
            x[5] = (__bf16)fabsf(a1.y - q1.y);
            x[6] = (__bf16)fabsf(a1.z - q1.z);
            x[7] = (__bf16)fabsf(a1.w - q1.w);
            *(bf16x8*)sp = x;
            fj += INF;
            sp += 16 * 272;
        }
    }
    __syncthreads();

    const bf16x8* w0v = (const bf16x8*)(ws + WS_W0BF);
    const bf16x8* w1v = (const bf16x8*)(ws + WS_W1BF);
    const float* bn0sw = (const float*)(ws + WS_BN0SW);
    const float* bn1sw = (const float*)(ws + WS_BN1SW);

    // ---- Layer 1: two nt-halves; acc 48 AGPR; results packed to bf16 regs --
    bf16x4 pk[2][3][4];
    #pragma unroll
    for (int h = 0; h < 2; ++h) {
        v4f acch[3][4];
        #pragma unroll
        for (int mt = 0; mt < 3; ++mt) {
            v4f bb = *(const v4f*)(bn0sw + (quad * 12 + wave * 3 + mt) * 4);
            #pragma unroll
            for (int nt = 0; nt < 4; ++nt)
                acch[mt][nt] = bb;
        }
        #pragma unroll
        for (int ks = 0; ks < 4; ++ks) {
            bf16x8 w0a = w0v[((wave * 3 + 0) * 4 + ks) * 64 + lane];
            bf16x8 w0b = w0v[((wave * 3 + 1) * 4 + ks) * 64 + lane];
            bf16x8 w0c = w0v[((wave * 3 + 2) * 4 + ks) * 64 + lane];
            #pragma unroll
            for (int nt = 0; nt < 4; ++nt) {
                bf16x8 xk = *(const bf16x8*)(smem +
                    ((h * 4 + nt) * 16 + l16) * 272 + ks * 64 + quad * 16);
                acch[0][nt] = __builtin_amdgcn_mfma_f32_16x16x32_bf16(
                    w0a, xk, acch[0][nt], 0, 0, 0);
                acch[1][nt] = __builtin_amdgcn_mfma_f32_16x16x32_bf16(
                    w0b, xk, acch[1][nt], 0, 0, 0);
                acch[2][nt] = __builtin_amdgcn_mfma_f32_16x16x32_bf16(
                    w0c, xk, acch[2][nt], 0, 0, 0);
            }
        }
        // leaky + pack -> bf16 VGPRs (frees the 48 AGPRs for the next half)
        #pragma unroll
        for (int mt = 0; mt < 3; ++mt)
            #pragma unroll
            for (int nt = 0; nt < 4; ++nt) {
                bf16x4 p;
                #pragma unroll
                for (int r = 0; r < 4; ++r) {
                    float v = acch[mt][nt][r];
                    v = fmaxf(v, 0.01f * v);
                    p[r] = (__bf16)v;
                }
                pk[h][mt][nt] = p;
            }
    }
    __syncthreads();   // all X reads done; H0 may overlay

    // ---- H0 write: 24 ds_write_b64 from the packed regs ----
    #pragma unroll
    for (int h = 0; h < 2; ++h)
        #pragma unroll
        for (int mt = 0; mt < 3; ++mt) {
            int chb = (wave * 3 + mt) * 16 + quad * 4;
            #pragma unroll
            for (int nt = 0; nt < 4; ++nt)
                *(bf16x4*)(smem + ((h * 4 + nt) * 16 + l16) * 400 + chb * 2)
                    = pk[h][mt][nt];
        }
    __syncthreads();   // H0 complete (cross-wave channels)

    // ---- Layer 2: wave owns pair ntiles {2w, 2w+1}; H0 rows are B-frags ----
    v4f acc2[6][2];
    #pragma unroll
    for (int mt = 0; mt < 6; ++mt) {
        v4f bb = *(const v4f*)(bn1sw + (quad * 6 + mt) * 4);
        acc2[mt][0] = bb;
        acc2[mt][1] = bb;
    }
    #pragma unroll
    for (int ks = 0; ks < 6; ++ks) {
        bf16x8 h0 = *(const bf16x8*)(smem + ((2 * wave + 0) * 16 + l16) * 400 + ks * 64 + quad * 16);
        bf16x8 h1 = *(const bf16x8*)(smem + ((2 * wave + 1) * 16 + l16) * 400 + ks * 64 + quad * 16);
        #pragma unroll
        for (int mt = 0; mt < 6; ++mt) {
            bf16x8 w = w1v[(mt * 6 + ks) * 64 + lane];
            acc2[mt][0] = __builtin_amdgcn_mfma_f32_16x16x32_bf16(w, h0, acc2[mt][0], 0, 0, 0);
            acc2[mt][1] = __builtin_amdgcn_mfma_f32_16x16x32_bf16(w, h1, acc2[mt][1], 0, 0, 0);
        }
    }

    // ---- epilogue: leaky + dot(wout) + cross-quad butterfly + sigmoid ----
    const float* woutsw = (const float*)(ws + WS_WOUTSW);
    float part[2] = {0.f, 0.f};
    #pragma unroll
    for (int mt = 0; mt < 6; ++mt) {
        v4f wo = *(const v4f*)(woutsw + (quad * 6 + mt) * 4);
        #pragma unroll
        for (int t = 0; t < 2; ++t)
            #pragma unroll
            for (int r = 0; r < 4; ++r) {
                float v = acc2[mt][t][r];
                v = fmaxf(v, 0.01f * v);
                part[t] = fmaf(v, wo[r], part[t]);
            }
    }
    #pragma unroll
    for (int t = 0; t < 2; ++t) {
        part[t] += __shfl_xor(part[t], 16, 64);
        part[t] += __shfl_xor(part[t], 32, 64);
    }
    float z = (quad & 1) ? part[1] : part[0];
    float sv = 1.f / (1.f + expf(-(z + boutp[0])));
    if (quad < 2)
        sim_out[(i0 + l16) * NN + jb + (quad & 1)] = sv;        // direct
    else
        sim_out[(jb + (quad & 1)) * NN + i0 + l16] = sv;        // mirror, 64B runs
}

// ---------------------------------------------------------------------------
// cinv via EXACT symmetry: colsum[j] == rowsum(sim[j][*]). [R9-verified]
// ---------------------------------------------------------------------------
__global__ __launch_bounds__(256) void cinv_kernel(
    const float* __restrict__ sim, float* __restrict__ cinv)
{
    const int lane = threadIdx.x & 63;
    const int wave = threadIdx.x >> 6;
    const float cadd = 1.0f + (float)NN * 1e-6f;
    #pragma unroll
    for (int rr = 0; rr < 4; ++rr) {
        int j = blockIdx.x * 16 + wave * 4 + rr;
        const float4* row = (const float4*)(sim + j * NN);
        float4 a0 = row[lane];
        float4 a1 = row[lane + 64];
        float4 a2 = row[lane + 128];
        float4 a3 = row[lane + 192];
        float s = (a0.x + a0.y + a0.z + a0.w) + (a1.x + a1.y + a1.z + a1.w)
                + (a2.x + a2.y + a2.z + a2.w) + (a3.x + a3.y + a3.z + a3.w);
        #pragma unroll
        for (int off = 1; off < 64; off <<= 1)
            s += __shfl_xor(s, off, 64);
        if (lane == 0)
            cinv[j] = 1.0f / (s + cadd);
    }
}

// ---------------------------------------------------------------------------
// edge[i][j] = (sim + eye + 1e-6) * cinv[j].
// ---------------------------------------------------------------------------
__global__ __launch_bounds__(256) void edge_kernel(
    const float* __restrict__ cinv, const float* __restrict__ sim,
    float* __restrict__ edge)
{
    int i = blockIdx.x;
    int jc = threadIdx.x << 2;
    float4 w = *(const float4*)(cinv + jc);
    float4 s = *(const float4*)(sim + i * NN + jc);
    float4 o;
    o.x = (s.x + (i == jc + 0 ? 1.f : 0.f) + 1e-6f) * w.x;
    o.y = (s.y + (i == jc + 1 ? 1.f : 0.f) + 1e-6f) * w.y;
    o.z = (s.z + (i == jc + 2 ? 1.f : 0.f) + 1e-6f) * w.z;
    o.w = (s.w + (i == jc + 3 ? 1.f : 0.f) + 1e-6f) * w.w;
    *(float4*)(edge + i * NN + jc) = o;
}

extern "C" void kernel_launch(void* const* d_in, const int* in_sizes, int n_in,
                              void* d_out, int out_size, void* d_ws, size_t ws_size,
                              hipStream_t stream)
{
    const float* feat = (const float*)d_in[0];
    const float* W0   = (const float*)d_in[1];
    const float* g0   = (const float*)d_in[2];
    const float* b0   = (const float*)d_in[3];
    const float* m0   = (const float*)d_in[4];
    const float* v0   = (const float*)d_in[5];
    const float* W1   = (const float*)d_in[6];
    const float* g1   = (const float*)d_in[7];
    const float* b1   = (const float*)d_in[8];
    const float* m1   = (const float*)d_in[9];
    const float* v1   = (const float*)d_in[10];
    const float* Wout = (const float*)d_in[11];
    const float* bout = (const float*)d_in[12];
    char* ws = (char*)d_ws;
    float* edge = (float*)d_out;
    float* sim  = edge + NN * NN;
    float* cinv = (float*)(ws + WS_CINV);

    prep_kernel<<<dim3(170), dim3(256), 0, stream>>>(
        W0, g0, b0, m0, v0, W1, g1, b1, m1, v1, Wout, ws);
    edgenet_main<<<dim3(4160), dim3(256), 0, stream>>>(feat, ws, bout, sim);
    cinv_kernel<<<dim3(64), dim3(256), 0, stream>>>(sim, cinv);
    edge_kernel<<<dim3(1024), dim3(256), 0, stream>>>(cinv, sim, edge);
}